// Round 5
// baseline (60.620 us; speedup 1.0000x reference)
//
#include <hip/hip_runtime.h>

#define COLS 4096
#define C4   (COLS / 4)
#define TROWS 4096
#define PAIRS (TROWS - 1)   // 4095
#define BCG   256           // col-groups (of 4 cols) per block
#define BCOLS 1024          // cols per block

// ---------------------------------------------------------------------------
// Mergeable run record (see round 3/4; verified absmax=0).
// Packed 16 B: x=hs y=ts z=ms w=bits[ hc:10 | tc:10 | mc:10 | ao:2 ]
// ---------------------------------------------------------------------------
struct Rec { float hs, hc, ts, tc, ms, mc, ao; };

__device__ inline Rec rec_merge(const Rec& L, const Rec& R) {
    Rec o;
    if (L.ao != 0.f && R.ao != 0.f) {
        o.hs = L.hs + R.hs; o.hc = L.hc + R.hc;
        o.ts = o.hs;        o.tc = o.hc;
        o.ms = 0.f; o.mc = 0.f; o.ao = 1.f;
    } else if (L.ao != 0.f) {
        o.hs = L.hs + R.hs; o.hc = L.hc + R.hc;
        o.ts = R.ts; o.tc = R.tc;
        o.ms = R.ms; o.mc = R.mc; o.ao = 0.f;
    } else if (R.ao != 0.f) {
        o.hs = L.hs; o.hc = L.hc;
        o.ts = L.ts + R.hs; o.tc = L.tc + R.hc;
        o.ms = L.ms; o.mc = L.mc; o.ao = 0.f;
    } else {
        o.hs = L.hs; o.hc = L.hc;
        o.ts = R.ts; o.tc = R.tc;
        float js = L.ts + R.hs, jc = L.tc + R.hc;
        bool v = jc > 0.f;
        o.ms = L.ms + R.ms + (v ? js / jc : 0.f);
        o.mc = L.mc + R.mc + (v ? 1.f : 0.f);
        o.ao = 0.f;
    }
    return o;
}

__device__ inline Rec rec16_load(const float4* base, size_t idx) {
    float4 a = base[idx];
    unsigned u = __float_as_uint(a.w);
    Rec r;
    r.hs = a.x; r.ts = a.y; r.ms = a.z;
    r.hc = (float)(u & 1023u);
    r.tc = (float)((u >> 10) & 1023u);
    r.mc = (float)((u >> 20) & 1023u);
    r.ao = (float)(u >> 30);
    return r;
}
__device__ inline Rec rec32_load(const float4* base, size_t idx) {
    float4 a = base[idx * 2], b = base[idx * 2 + 1];
    Rec r; r.hs = a.x; r.hc = a.y; r.ts = a.z; r.tc = a.w;
    r.ms = b.x; r.mc = b.y; r.ao = b.z; return r;
}
__device__ inline void rec32_store(float4* base, size_t idx, const Rec& r) {
    base[idx * 2]     = make_float4(r.hs, r.hc, r.ts, r.tc);
    base[idx * 2 + 1] = make_float4(r.ms, r.mc, r.ao, 0.f);
}

// async 16B/lane global -> LDS (zero VGPR cost for in-flight data)
__device__ __forceinline__ void async16(const void* g, void* l) {
    __builtin_amdgcn_global_load_lds(
        (const __attribute__((address_space(1))) void*)g,
        (__attribute__((address_space(3))) void*)l, 16, 0, 0);
}

// ---------------------------------------------------------------------------
// Phase 1: block stages (up to) 9 rows x 1024 cols of P and S into LDS via
// global_load_lds (72 KB, 2 blocks/CU), then each thread scans 4 cols from
// LDS. Scan state carries across 8-pair stages in registers, so only the
// first stage loads the chunk's boundary row. Emits packed 16 B records.
// ---------------------------------------------------------------------------
__global__ __launch_bounds__(256)
void msi_phase1(const float4* __restrict__ p4, const int4* __restrict__ s4,
                float4* __restrict__ recs, int PCH) {
    __shared__ __align__(16) float lp[9][BCOLS];
    __shared__ __align__(16) int   lsd[9][BCOLS];

    int tid  = threadIdx.x;
    int wave = tid >> 6, lane = tid & 63;
    int colg0 = blockIdx.x * BCG;      // global col-group base of this block
    int c = blockIdx.y;
    int t0 = c * PCH;
    int t1 = t0 + PCH; if (t1 > PAIRS) t1 = PAIRS;

    // per-lane global pointers (each wave stages its own quarter-row)
    const float4* gp = p4 + colg0 + (wave << 6) + lane;
    const int4*   gs = s4 + colg0 + (wave << 6) + lane;
    // wave-uniform LDS bases (lane*16B is appended by hardware)
    float* lpw = &lp[0][0] + (wave << 8);   // wave*256 floats = 1 KB
    int*   lsw = &lsd[0][0] + (wave << 8);

    float pprev[4]; int sprev[4];
    float cs[4] = {0.f, 0.f, 0.f, 0.f};
    int   cc[4] = {0, 0, 0, 0};
    float hs[4] = {0.f, 0.f, 0.f, 0.f};
    int   hc[4] = {0, 0, 0, 0};
    int   hd[4] = {0, 0, 0, 0};
    float ms[4] = {0.f, 0.f, 0.f, 0.f};
    int   mc[4] = {0, 0, 0, 0};

    bool first = true;
    for (int ts = t0; ts < t1; ts += 8) {
        int te = ts + 8; if (te > t1) te = t1;

        if (!first) __syncthreads();   // prior stage fully consumed before overwrite

        if (first) {                   // boundary row -> LDS row 0
            async16(gp + (size_t)t0 * C4, lpw);
            async16(gs + (size_t)t0 * C4, lsw);
        }
        for (int r = ts + 1; r <= te; ++r) {
            int ri = r - ts;           // 1..8
            async16(gp + (size_t)r * C4, lpw + ri * BCOLS);
            async16(gs + (size_t)r * C4, lsw + ri * BCOLS);
        }
        asm volatile("s_waitcnt vmcnt(0)" ::: "memory");
        __syncthreads();

        if (first) {
            float4 P = *(const float4*)&lp[0][tid << 2];
            int4   S = *(const int4*)&lsd[0][tid << 2];
            pprev[0] = P.x; pprev[1] = P.y; pprev[2] = P.z; pprev[3] = P.w;
            sprev[0] = S.x; sprev[1] = S.y; sprev[2] = S.z; sprev[3] = S.w;
            first = false;
        }

        for (int t = ts; t < te; ++t) {
            int ri = t - ts + 1;
            float4 PV = *(const float4*)&lp[ri][tid << 2];
            int4   SV = *(const int4*)&lsd[ri][tid << 2];
            float pcur[4] = {PV.x, PV.y, PV.z, PV.w};
            int   scur[4] = {SV.x, SV.y, SV.z, SV.w};
            #pragma unroll
            for (int k = 0; k < 4; ++k) {
                float d = pcur[k] - pprev[k];
                bool same = (scur[k] == sprev[k]);
                bool firstk = !same && !hd[k];
                bool interior = !same && hd[k] && (cc[k] > 0);
                hs[k] = firstk ? cs[k] : hs[k];
                hc[k] = firstk ? cc[k] : hc[k];
                float mean = cs[k] * __builtin_amdgcn_rcpf((float)cc[k]);
                ms[k] += interior ? mean : 0.f;
                mc[k] += interior ? 1 : 0;
                hd[k] = hd[k] | (same ? 0 : 1);
                cs[k] = same ? cs[k] + d * d : 0.f;
                cc[k] = same ? cc[k] + 1 : 0;
                pprev[k] = pcur[k];
                sprev[k] = scur[k];
            }
        }
    }

    // Emit 4 packed 16 B records (64 B contiguous per thread).
    #pragma unroll
    for (int k = 0; k < 4; ++k) {
        int r = 4 * (colg0 + tid) + k;
        float4 a;
        if (!hd[k]) {
            unsigned u = (unsigned)cc[k] | ((unsigned)cc[k] << 10) | (3u << 30);
            a = make_float4(cs[k], cs[k], 0.f, __uint_as_float(u));
        } else {
            unsigned u = (unsigned)hc[k] | ((unsigned)cc[k] << 10) |
                         ((unsigned)mc[k] << 20);
            a = make_float4(hs[k], cs[k], ms[k], __uint_as_float(u));
        }
        recs[(size_t)c * COLS + r] = a;
    }
}

// ---------------------------------------------------------------------------
// Phase 2a: merge G consecutive chunk-records per column into a 32 B super.
// ---------------------------------------------------------------------------
__global__ void msi_phase2a(const float4* __restrict__ recs, float4* __restrict__ supers,
                            int G) {
    int r = blockIdx.x * blockDim.x + threadIdx.x;
    int sup = blockIdx.y;
    size_t base = (size_t)sup * G * COLS + r;
    Rec acc = rec16_load(recs, base);
    #pragma unroll 4
    for (int j = 1; j < G; ++j) {
        Rec nxt = rec16_load(recs, base + (size_t)j * COLS);
        acc = rec_merge(acc, nxt);
    }
    rec32_store(supers, (size_t)sup * COLS + r, acc);
}

// ---------------------------------------------------------------------------
// Phase 2b: merge NSUP supers per column, finalize, block-reduce in double.
// ---------------------------------------------------------------------------
__global__ void msi_phase2b(const float4* __restrict__ supers, double* __restrict__ partials,
                            int NSUP) {
    int r = blockIdx.x * blockDim.x + threadIdx.x;
    Rec acc = rec32_load(supers, r);
    for (int j = 1; j < NSUP; ++j)
        acc = rec_merge(acc, rec32_load(supers, (size_t)j * COLS + r));

    double msum, mcnt;
    if (acc.ao != 0.f) {
        bool v = acc.hc > 0.f;
        msum = v ? (double)(acc.hs / acc.hc) : 0.0;
        mcnt = v ? 1.0 : 0.0;
    } else {
        msum = (double)acc.ms; mcnt = (double)acc.mc;
        if (acc.hc > 0.f) { msum += (double)(acc.hs / acc.hc); mcnt += 1.0; }
        if (acc.tc > 0.f) { msum += (double)(acc.ts / acc.tc); mcnt += 1.0; }
    }

    __shared__ double ls[256];
    __shared__ double lc[256];
    int tid = threadIdx.x;
    ls[tid] = msum; lc[tid] = mcnt;
    __syncthreads();
    for (int off = 128; off > 0; off >>= 1) {
        if (tid < off) { ls[tid] += ls[tid + off]; lc[tid] += lc[tid + off]; }
        __syncthreads();
    }
    if (tid == 0) {
        partials[blockIdx.x * 2 + 0] = ls[0];
        partials[blockIdx.x * 2 + 1] = lc[0];
    }
}

__global__ void msi_phase3(const double* __restrict__ partials, int nparts,
                           float* __restrict__ out) {
    int tid = threadIdx.x;
    double msum = 0.0, mcnt = 0.0;
    if (tid < nparts) {
        msum = partials[tid * 2 + 0];
        mcnt = partials[tid * 2 + 1];
    }
    for (int off = 32; off > 0; off >>= 1) {
        msum += __shfl_down(msum, off);
        mcnt += __shfl_down(mcnt, off);
    }
    if (tid == 0) out[0] = (mcnt > 0.0) ? (float)(msum / mcnt) : 0.f;
}

extern "C" void kernel_launch(void* const* d_in, const int* in_sizes, int n_in,
                              void* d_out, int out_size, void* d_ws, size_t ws_size,
                              hipStream_t stream) {
    const float4* p = (const float4*)d_in[0];
    const int4*   s = (const int4*)d_in[1];
    float* out = (float*)d_out;

    const int nblocks2 = COLS / 256;  // 16
    int NC = 512;
    auto need = [&](int nc) -> size_t {
        int gg = nc < 16 ? nc : 16;
        int nsup = nc / gg;
        return (size_t)nc * COLS * 16 + (size_t)nsup * COLS * 32 +
               (size_t)nblocks2 * 2 * sizeof(double);
    };
    while (NC > 8 && need(NC) > ws_size) NC >>= 1;
    int G = NC < 16 ? NC : 16;
    int NSUP = NC / G;
    int PCH = (PAIRS + NC - 1) / NC;

    float4* recs     = (float4*)d_ws;                 // NC*COLS packed 16B recs
    float4* supers   = recs + (size_t)NC * COLS;      // NSUP*COLS 32B recs
    double* partials = (double*)(supers + (size_t)NSUP * COLS * 2);

    dim3 g1(COLS / BCOLS, NC);     // (4, NC) blocks of 256
    msi_phase1<<<g1, 256, 0, stream>>>(p, s, recs, PCH);
    dim3 g2a(COLS / 256, NSUP);
    msi_phase2a<<<g2a, 256, 0, stream>>>(recs, supers, G);
    msi_phase2b<<<nblocks2, 256, 0, stream>>>(supers, partials, NSUP);
    msi_phase3<<<1, 64, 0, stream>>>(partials, nblocks2, out);
}

// Round 6
// 44.742 us; speedup vs baseline: 1.3549x; 1.3549x over previous
//
#include <hip/hip_runtime.h>

#define COLS 4096
#define C4   (COLS / 4)
#define TROWS 4096
#define PAIRS (TROWS - 1)   // 4095
#define BCOLS 1024          // cols per block
#define BCG   (BCOLS / 4)   // col-groups (of 4 cols) per block
#define SR    4             // pair-rows per pipeline stage

// ---------------------------------------------------------------------------
// Mergeable run record (verified absmax=0 rounds 3-5).
// Packed 16 B: x=hs y=ts z=ms w=bits[ hc:10 | tc:10 | mc:10 | ao:2 ]
// ---------------------------------------------------------------------------
struct Rec { float hs, hc, ts, tc, ms, mc, ao; };

__device__ inline Rec rec_merge(const Rec& L, const Rec& R) {
    Rec o;
    if (L.ao != 0.f && R.ao != 0.f) {
        o.hs = L.hs + R.hs; o.hc = L.hc + R.hc;
        o.ts = o.hs;        o.tc = o.hc;
        o.ms = 0.f; o.mc = 0.f; o.ao = 1.f;
    } else if (L.ao != 0.f) {
        o.hs = L.hs + R.hs; o.hc = L.hc + R.hc;
        o.ts = R.ts; o.tc = R.tc;
        o.ms = R.ms; o.mc = R.mc; o.ao = 0.f;
    } else if (R.ao != 0.f) {
        o.hs = L.hs; o.hc = L.hc;
        o.ts = L.ts + R.hs; o.tc = L.tc + R.hc;
        o.ms = L.ms; o.mc = L.mc; o.ao = 0.f;
    } else {
        o.hs = L.hs; o.hc = L.hc;
        o.ts = R.ts; o.tc = R.tc;
        float js = L.ts + R.hs, jc = L.tc + R.hc;
        bool v = jc > 0.f;
        o.ms = L.ms + R.ms + (v ? js / jc : 0.f);
        o.mc = L.mc + R.mc + (v ? 1.f : 0.f);
        o.ao = 0.f;
    }
    return o;
}

__device__ inline Rec rec16_load(const float4* base, size_t idx) {
    float4 a = base[idx];
    unsigned u = __float_as_uint(a.w);
    Rec r;
    r.hs = a.x; r.ts = a.y; r.ms = a.z;
    r.hc = (float)(u & 1023u);
    r.tc = (float)((u >> 10) & 1023u);
    r.mc = (float)((u >> 20) & 1023u);
    r.ao = (float)(u >> 30);
    return r;
}
__device__ inline Rec rec32_load(const float4* base, size_t idx) {
    float4 a = base[idx * 2], b = base[idx * 2 + 1];
    Rec r; r.hs = a.x; r.hc = a.y; r.ts = a.z; r.tc = a.w;
    r.ms = b.x; r.mc = b.y; r.ao = b.z; return r;
}
__device__ inline void rec32_store(float4* base, size_t idx, const Rec& r) {
    base[idx * 2]     = make_float4(r.hs, r.hc, r.ts, r.tc);
    base[idx * 2 + 1] = make_float4(r.ms, r.mc, r.ao, 0.f);
}

// async 16B/lane global -> LDS (zero VGPR cost for in-flight data)
__device__ __forceinline__ void async16(const void* g, void* l) {
    __builtin_amdgcn_global_load_lds(
        (const __attribute__((address_space(1))) void*)g,
        (__attribute__((address_space(3))) void*)l, 16, 0, 0);
}

// ---------------------------------------------------------------------------
// Phase 1: double-buffered DMA pipeline, wave-private LDS slices (no
// __syncthreads). Per stage: issue next stage's 8 global_load_lds into buf^1,
// s_waitcnt vmcnt(8) (current stage complete, next stays IN FLIGHT), consume
// 4 pair-rows from buf, flip. Emits packed 16 B records per column.
// ---------------------------------------------------------------------------
__global__ __launch_bounds__(256)
void msi_phase1(const float4* __restrict__ p4, const int4* __restrict__ s4,
                float4* __restrict__ recs, int PCH) {
    __shared__ __align__(16) float lp[2][SR][BCOLS];   // 32 KB
    __shared__ __align__(16) int   lsd[2][SR][BCOLS];  // 32 KB
    __shared__ __align__(16) float lpB[BCOLS];         // 4 KB boundary row
    __shared__ __align__(16) int   lsB[BCOLS];         // 4 KB

    const int tid  = threadIdx.x;
    const int wave = tid >> 6, lane = tid & 63;
    const int colg0 = blockIdx.x * BCG;
    const int c = blockIdx.y;
    const int t0 = c * PCH;
    int t1 = t0 + PCH; if (t1 > PAIRS) t1 = PAIRS;

    const float4* gp = p4 + colg0 + (wave << 6) + lane;
    const int4*   gs = s4 + colg0 + (wave << 6) + lane;
    const int woff = wave << 8;          // wave slice: 256 floats/ints

    // issue one stage (always exactly 8 loads; rows clamped to t1 so the
    // vmcnt count is compile-time constant; clamped slots are never read)
    auto issue_stage = [&](int B, int ts) {
        #pragma unroll
        for (int j = 1; j <= SR; ++j) {
            int r = ts + j; if (r > t1) r = t1;
            async16(gp + (size_t)r * C4, &lp[B][j - 1][0] + woff);
            async16(gs + (size_t)r * C4, &lsd[B][j - 1][0] + woff);
        }
    };

    float pprev[4]; int sprev[4];
    float cs[4] = {0.f, 0.f, 0.f, 0.f};
    int   cc[4] = {0, 0, 0, 0};
    float hs[4] = {0.f, 0.f, 0.f, 0.f};
    int   hc[4] = {0, 0, 0, 0};
    int   hd[4] = {0, 0, 0, 0};
    float ms[4] = {0.f, 0.f, 0.f, 0.f};
    int   mc[4] = {0, 0, 0, 0};

    // prologue: boundary row + stage 0
    async16(gp + (size_t)t0 * C4, &lpB[0] + woff);
    async16(gs + (size_t)t0 * C4, &lsB[0] + woff);
    issue_stage(0, t0);

    const int nst = (t1 - t0 + SR - 1) / SR;
    int cur = 0;
    bool first = true;
    for (int st = 0; st < nst; ++st) {
        int ts = t0 + st * SR;
        int nr = t1 - ts; if (nr > SR) nr = SR;

        // my prior ds_reads of buf[cur^1] are drained (results were consumed);
        // explicit wait is ~free and guards the DMA-overwrite hazard.
        asm volatile("s_waitcnt lgkmcnt(0)" ::: "memory");
        if (st + 1 < nst) {
            issue_stage(cur ^ 1, ts + SR);
            asm volatile("s_waitcnt vmcnt(8)" ::: "memory");  // stage st done, st+1 in flight
        } else {
            asm volatile("s_waitcnt vmcnt(0)" ::: "memory");  // final drain
        }

        if (first) {
            float4 P = *(const float4*)(&lpB[0] + (tid << 2));
            int4   S = *(const int4*)(&lsB[0] + (tid << 2));
            pprev[0] = P.x; pprev[1] = P.y; pprev[2] = P.z; pprev[3] = P.w;
            sprev[0] = S.x; sprev[1] = S.y; sprev[2] = S.z; sprev[3] = S.w;
            first = false;
        }

        #pragma unroll
        for (int j = 0; j < SR; ++j) {
            if (j >= nr) break;
            float4 PV = *(const float4*)(&lp[cur][j][0] + (tid << 2));
            int4   SV = *(const int4*)(&lsd[cur][j][0] + (tid << 2));
            float pcur[4] = {PV.x, PV.y, PV.z, PV.w};
            int   scur[4] = {SV.x, SV.y, SV.z, SV.w};
            #pragma unroll
            for (int k = 0; k < 4; ++k) {
                float d = pcur[k] - pprev[k];
                bool same = (scur[k] == sprev[k]);
                bool firstk = !same && !hd[k];
                bool interior = !same && hd[k] && (cc[k] > 0);
                hs[k] = firstk ? cs[k] : hs[k];
                hc[k] = firstk ? cc[k] : hc[k];
                float mean = cs[k] * __builtin_amdgcn_rcpf((float)cc[k]);
                ms[k] += interior ? mean : 0.f;
                mc[k] += interior ? 1 : 0;
                hd[k] = hd[k] | (same ? 0 : 1);
                cs[k] = same ? cs[k] + d * d : 0.f;
                cc[k] = same ? cc[k] + 1 : 0;
                pprev[k] = pcur[k];
                sprev[k] = scur[k];
            }
        }
        cur ^= 1;
    }

    // Emit 4 packed 16 B records (64 B contiguous per thread).
    #pragma unroll
    for (int k = 0; k < 4; ++k) {
        int r = 4 * (colg0 + tid) + k;
        float4 a;
        if (!hd[k]) {
            unsigned u = (unsigned)cc[k] | ((unsigned)cc[k] << 10) | (3u << 30);
            a = make_float4(cs[k], cs[k], 0.f, __uint_as_float(u));
        } else {
            unsigned u = (unsigned)hc[k] | ((unsigned)cc[k] << 10) |
                         ((unsigned)mc[k] << 20);
            a = make_float4(hs[k], cs[k], ms[k], __uint_as_float(u));
        }
        recs[(size_t)c * COLS + r] = a;
    }
}

// ---------------------------------------------------------------------------
// Phase 2a: merge G consecutive chunk-records per column into a 32 B super.
// ---------------------------------------------------------------------------
__global__ void msi_phase2a(const float4* __restrict__ recs, float4* __restrict__ supers,
                            int G) {
    int r = blockIdx.x * blockDim.x + threadIdx.x;
    int sup = blockIdx.y;
    size_t base = (size_t)sup * G * COLS + r;
    Rec acc = rec16_load(recs, base);
    #pragma unroll 4
    for (int j = 1; j < G; ++j) {
        Rec nxt = rec16_load(recs, base + (size_t)j * COLS);
        acc = rec_merge(acc, nxt);
    }
    rec32_store(supers, (size_t)sup * COLS + r, acc);
}

// ---------------------------------------------------------------------------
// Phase 2b: merge NSUP supers per column, finalize, block-reduce in double.
// ---------------------------------------------------------------------------
__global__ void msi_phase2b(const float4* __restrict__ supers, double* __restrict__ partials,
                            int NSUP) {
    int r = blockIdx.x * blockDim.x + threadIdx.x;
    Rec acc = rec32_load(supers, r);
    for (int j = 1; j < NSUP; ++j)
        acc = rec_merge(acc, rec32_load(supers, (size_t)j * COLS + r));

    double msum, mcnt;
    if (acc.ao != 0.f) {
        bool v = acc.hc > 0.f;
        msum = v ? (double)(acc.hs / acc.hc) : 0.0;
        mcnt = v ? 1.0 : 0.0;
    } else {
        msum = (double)acc.ms; mcnt = (double)acc.mc;
        if (acc.hc > 0.f) { msum += (double)(acc.hs / acc.hc); mcnt += 1.0; }
        if (acc.tc > 0.f) { msum += (double)(acc.ts / acc.tc); mcnt += 1.0; }
    }

    __shared__ double ls[256];
    __shared__ double lc[256];
    int tid = threadIdx.x;
    ls[tid] = msum; lc[tid] = mcnt;
    __syncthreads();
    for (int off = 128; off > 0; off >>= 1) {
        if (tid < off) { ls[tid] += ls[tid + off]; lc[tid] += lc[tid + off]; }
        __syncthreads();
    }
    if (tid == 0) {
        partials[blockIdx.x * 2 + 0] = ls[0];
        partials[blockIdx.x * 2 + 1] = lc[0];
    }
}

__global__ void msi_phase3(const double* __restrict__ partials, int nparts,
                           float* __restrict__ out) {
    int tid = threadIdx.x;
    double msum = 0.0, mcnt = 0.0;
    if (tid < nparts) {
        msum = partials[tid * 2 + 0];
        mcnt = partials[tid * 2 + 1];
    }
    for (int off = 32; off > 0; off >>= 1) {
        msum += __shfl_down(msum, off);
        mcnt += __shfl_down(mcnt, off);
    }
    if (tid == 0) out[0] = (mcnt > 0.0) ? (float)(msum / mcnt) : 0.f;
}

extern "C" void kernel_launch(void* const* d_in, const int* in_sizes, int n_in,
                              void* d_out, int out_size, void* d_ws, size_t ws_size,
                              hipStream_t stream) {
    const float4* p = (const float4*)d_in[0];
    const int4*   s = (const int4*)d_in[1];
    float* out = (float*)d_out;

    const int nblocks2 = COLS / 256;  // 16
    int NC = 128;                     // 512 blocks = 2/CU exactly; PCH=32 (8 stages)
    auto need = [&](int nc) -> size_t {
        int gg = nc < 16 ? nc : 16;
        int nsup = nc / gg;
        return (size_t)nc * COLS * 16 + (size_t)nsup * COLS * 32 +
               (size_t)nblocks2 * 2 * sizeof(double);
    };
    while (NC > 8 && need(NC) > ws_size) NC >>= 1;
    int G = NC < 16 ? NC : 16;
    int NSUP = NC / G;
    int PCH = (PAIRS + NC - 1) / NC;

    float4* recs     = (float4*)d_ws;                 // NC*COLS packed 16B recs
    float4* supers   = recs + (size_t)NC * COLS;      // NSUP*COLS 32B recs
    double* partials = (double*)(supers + (size_t)NSUP * COLS * 2);

    dim3 g1(COLS / BCOLS, NC);     // (4, NC) blocks of 256
    msi_phase1<<<g1, 256, 0, stream>>>(p, s, recs, PCH);
    dim3 g2a(COLS / 256, NSUP);
    msi_phase2a<<<g2a, 256, 0, stream>>>(recs, supers, G);
    msi_phase2b<<<nblocks2, 256, 0, stream>>>(supers, partials, NSUP);
    msi_phase3<<<1, 64, 0, stream>>>(partials, nblocks2, out);
}